// Round 4
// baseline (1008.358 us; speedup 1.0000x reference)
//
#include <hip/hip_runtime.h>
#include <hip/hip_bf16.h>
#include <math.h>

#define NN 20000
#define NE 320000

typedef unsigned short ushort_t;
typedef unsigned short ushortx8 __attribute__((ext_vector_type(8)));

__device__ __forceinline__ float us2f(unsigned short u){
  return __uint_as_float(((unsigned)u) << 16);
}
__device__ __forceinline__ unsigned short f2us(float f){
  unsigned u = __float_as_uint(f);
  unsigned r = (u + 0x7fffu + ((u >> 16) & 1u)) >> 16;   // RNE
  return (unsigned short)r;
}

// ---------------- CSR build ----------------
__global__ void k_zero(int* p, int n){
  int i = blockIdx.x * 256 + threadIdx.x;
  if (i < n) p[i] = 0;
}

__global__ void k_hist(const int* __restrict__ ei, int* __restrict__ deg){
  int e = blockIdx.x * 256 + threadIdx.x;
  if (e < NE) atomicAdd(&deg[ei[NE + e]], 1);
}

__global__ __launch_bounds__(1024) void k_scan(const int* __restrict__ deg,
                                               int* __restrict__ rowst,
                                               int* __restrict__ cur){
  __shared__ int s[1024];
  __shared__ int carry_s;
  int tid = threadIdx.x;
  if (tid == 0) carry_s = 0;
  __syncthreads();
  for (int base = 0; base < NN; base += 1024){
    int v = (base + tid < NN) ? deg[base + tid] : 0;
    s[tid] = v; __syncthreads();
    for (int off = 1; off < 1024; off <<= 1){
      int t = (tid >= off) ? s[tid - off] : 0;
      __syncthreads();
      s[tid] += t;
      __syncthreads();
    }
    int carry = carry_s;
    int excl = carry + s[tid] - v;
    if (base + tid < NN){ rowst[base + tid] = excl; cur[base + tid] = excl; }
    __syncthreads();
    if (tid == 0) carry_s = carry + s[1023];
    __syncthreads();
  }
  if (tid == 0) rowst[NN] = carry_s;
}

__global__ void k_scatter(const int* __restrict__ ei, int* __restrict__ cur,
                          int* __restrict__ csr){
  int e = blockIdx.x * 256 + threadIdx.x;
  if (e < NE){
    int d = ei[NE + e];
    int p = atomicAdd(&cur[d], 1);
    csr[p] = e;
  }
}

// ---------------- input projection: h = x@Win + b_in ----------------
__global__ __launch_bounds__(128) void k_inproj(const float* __restrict__ x,
                                                const float* __restrict__ Win,
                                                const float* __restrict__ bin,
                                                float* __restrict__ h){
  __shared__ float sW[32 * 128];
  __shared__ float sx[4][32];
  int tid = threadIdx.x;
  for (int i = 0; i < 32; i++) sW[i * 128 + tid] = Win[i * 128 + tid];
  int r0 = blockIdx.x * 4;
  {
    int r = tid >> 5, kk = tid & 31;
    int gr = r0 + r;
    sx[r][kk] = (gr < NN) ? x[gr * 32 + kk] : 0.f;
  }
  __syncthreads();
  float bias = bin[tid];
  for (int r = 0; r < 4; r++){
    int gr = r0 + r;
    if (gr >= NN) break;
    float acc = bias;
    #pragma unroll
    for (int k2 = 0; k2 < 32; k2++) acc += sx[r][k2] * sW[k2 * 128 + tid];
    h[(size_t)gr * 128 + tid] = acc;
  }
}

// ---------------- LayerNorm (wave per row) ----------------
__global__ void k_ln(const float* __restrict__ in, const float* __restrict__ sc,
                     const float* __restrict__ bi, float* __restrict__ outp, int rows){
  int row = blockIdx.x * 4 + (threadIdx.x >> 6);
  int lane = threadIdx.x & 63;
  if (row >= rows) return;
  const float* p = in + (size_t)row * 128 + lane * 2;
  float x0 = p[0], x1 = p[1];
  float sum = x0 + x1;
  for (int m = 1; m < 64; m <<= 1) sum += __shfl_xor(sum, m);
  float mean = sum * (1.f / 128.f);
  float d0 = x0 - mean, d1 = x1 - mean;
  float vs = d0 * d0 + d1 * d1;
  for (int m = 1; m < 64; m <<= 1) vs += __shfl_xor(vs, m);
  float rstd = rsqrtf(vs * (1.f / 128.f) + 1e-5f);
  int d = lane * 2;
  float* o = outp + (size_t)row * 128 + d;
  o[0] = d0 * rstd * sc[d] + bi[d];
  o[1] = d1 * rstd * sc[d + 1] + bi[d + 1];
}

// ------- GEMM: C[M,N] = A[M,K] @ B[K,N](f32) + bias -------
// MODE 0: plain   MODE 1: gelu(exact)   MODE 2: C(f32) += g * (acc+bias)
// ABF16: A stored as bf16   CBF16: C stored as bf16 (MODE 0/1 only)
template<int MODE, int ABF16, int CBF16>
__global__ __launch_bounds__(256) void k_gemm(const void* __restrict__ Ap, int lda, int M,
                                              const float* __restrict__ B, int ldb,
                                              const float* __restrict__ bias,
                                              void* __restrict__ Cp, int ldc, int K,
                                              const float* __restrict__ gptr){
  __shared__ float As[64 * 68];   // [k][row], padded
  __shared__ float Bs[64 * 68];   // [k][col], padded
  int tid = threadIdx.x;
  int m0 = blockIdx.x * 64, n0 = blockIdx.y * 64;
  int tr = tid >> 4, tc = tid & 15;
  float acc[4][4] = {};
  for (int k0 = 0; k0 < K; k0 += 64){
    __syncthreads();
    #pragma unroll
    for (int it = 0; it < 4; it++){
      int lin = tid + it * 256;
      int row = lin >> 4; int kq = (lin & 15) * 4;
      int gr = m0 + row; if (gr >= M) gr = M - 1;
      float a0, a1, a2, a3;
      if (ABF16){
        const ushort_t* A16 = (const ushort_t*)Ap;
        ushort4 a4 = *(const ushort4*)(A16 + (size_t)gr * lda + k0 + kq);
        a0 = us2f(a4.x); a1 = us2f(a4.y); a2 = us2f(a4.z); a3 = us2f(a4.w);
      } else {
        const float* Af = (const float*)Ap;
        float4 a4 = *(const float4*)(Af + (size_t)gr * lda + k0 + kq);
        a0 = a4.x; a1 = a4.y; a2 = a4.z; a3 = a4.w;
      }
      As[(kq + 0) * 68 + row] = a0;
      As[(kq + 1) * 68 + row] = a1;
      As[(kq + 2) * 68 + row] = a2;
      As[(kq + 3) * 68 + row] = a3;
    }
    #pragma unroll
    for (int it = 0; it < 4; it++){
      int lin = tid + it * 256;
      int kk = lin >> 4; int cq = (lin & 15) * 4;
      float4 b4 = *(const float4*)(B + (size_t)(k0 + kk) * ldb + n0 + cq);
      *(float4*)&Bs[kk * 68 + cq] = b4;
    }
    __syncthreads();
    #pragma unroll 8
    for (int kk = 0; kk < 64; kk++){
      float4 a4 = *(const float4*)&As[kk * 68 + tr * 4];
      float4 b4 = *(const float4*)&Bs[kk * 68 + tc * 4];
      float av[4] = {a4.x, a4.y, a4.z, a4.w};
      float bv[4] = {b4.x, b4.y, b4.z, b4.w};
      #pragma unroll
      for (int i = 0; i < 4; i++)
        #pragma unroll
        for (int j = 0; j < 4; j++) acc[i][j] += av[i] * bv[j];
    }
  }
  float g = (MODE == 2) ? *gptr : 0.f;
  for (int i = 0; i < 4; i++){
    int gr = m0 + tr * 4 + i;
    if (gr >= M) break;
    float cv[4];
    #pragma unroll
    for (int j = 0; j < 4; j++){
      int gc = n0 + tc * 4 + j;
      float c = acc[i][j] + bias[gc];
      if (MODE == 1) c = 0.5f * c * (1.f + erff(c * 0.70710678118654752f));
      cv[j] = c;
    }
    int gc0 = n0 + tc * 4;
    if (MODE == 2){
      float* C = (float*)Cp;
      #pragma unroll
      for (int j = 0; j < 4; j++) C[(size_t)gr * ldc + gc0 + j] += g * cv[j];
    } else if (CBF16){
      ushort_t* C = (ushort_t*)Cp;
      ushort4 pk; pk.x = f2us(cv[0]); pk.y = f2us(cv[1]); pk.z = f2us(cv[2]); pk.w = f2us(cv[3]);
      *(ushort4*)(C + (size_t)gr * ldc + gc0) = pk;
    } else {
      float* C = (float*)Cp;
      #pragma unroll
      for (int j = 0; j < 4; j++) C[(size_t)gr * ldc + gc0 + j] = cv[j];
    }
  }
}

// ---------------- per-edge attention logits (q,k in bf16) ----------------
__global__ void k_alpha(const ushort_t* __restrict__ q, const ushort_t* __restrict__ k,
                        const int* __restrict__ ei, float* __restrict__ al){
  int e = blockIdx.x * 4 + (threadIdx.x >> 6);
  int lane = threadIdx.x & 63;
  if (e >= NE) return;
  int s = ei[e], d = ei[NE + e];
  ushortx8 qv = *((const ushortx8*)(q + (size_t)d * 512) + lane);
  ushortx8 kv = *((const ushortx8*)(k + (size_t)s * 512) + lane);
  float p = 0.f;
  #pragma unroll
  for (int j = 0; j < 8; j++) p += us2f(qv[j]) * us2f(kv[j]);
  p += __shfl_xor(p, 1); p += __shfl_xor(p, 2);
  p += __shfl_xor(p, 4); p += __shfl_xor(p, 8);
  if ((lane & 15) == 0) al[(size_t)e * 4 + (lane >> 4)] = p * 0.08838834764831845f;
}

// ---------------- per-node softmax + aggregation (wave per node, v in bf16) ----------------
__global__ void k_node(const float* __restrict__ al, const ushort_t* __restrict__ v,
                       const int* __restrict__ ei, const int* __restrict__ rowst,
                       const int* __restrict__ csr, float* __restrict__ ob){
  int n = blockIdx.x * 4 + (threadIdx.x >> 6);
  int lane = threadIdx.x & 63;
  if (n >= NN) return;
  int s0 = rowst[n], s1 = rowst[n + 1];
  int deg = s1 - s0;
  if (deg == 0){
    if (lane < 16){
      float4 z = make_float4(0.f, 0.f, 0.f, 0.f);
      float4* op = (float4*)(ob + (size_t)n * 128 + lane * 8);
      op[0] = z; op[1] = z;
    }
    return;
  }
  int head = lane >> 4, sub = lane & 15;
  float m = -1e30f;
  for (int j = sub; j < deg; j += 16) m = fmaxf(m, al[(size_t)csr[s0 + j] * 4 + head]);
  m = fmaxf(m, __shfl_xor(m, 1)); m = fmaxf(m, __shfl_xor(m, 2));
  m = fmaxf(m, __shfl_xor(m, 4)); m = fmaxf(m, __shfl_xor(m, 8));
  float den = 0.f;
  for (int j = sub; j < deg; j += 16) den += __expf(al[(size_t)csr[s0 + j] * 4 + head] - m);
  den += __shfl_xor(den, 1); den += __shfl_xor(den, 2);
  den += __shfl_xor(den, 4); den += __shfl_xor(den, 8);
  float acc[8] = {0.f, 0.f, 0.f, 0.f, 0.f, 0.f, 0.f, 0.f};
  for (int j = 0; j < deg; j++){
    int e = csr[s0 + j];
    float w = __expf(al[(size_t)e * 4 + head] - m);
    ushortx8 vv = *((const ushortx8*)(v + (size_t)ei[e] * 512) + lane);
    #pragma unroll
    for (int t = 0; t < 8; t++) acc[t] += w * us2f(vv[t]);
  }
  float inv = 0.25f / den;   // mean over 4 heads folded in
  #pragma unroll
  for (int t = 0; t < 8; t++){
    float r = acc[t] * inv;
    r += __shfl_xor(r, 16); r += __shfl_xor(r, 32);
    acc[t] = r;
  }
  if (lane < 16){
    float4* op = (float4*)(ob + (size_t)n * 128 + lane * 8);
    op[0] = make_float4(acc[0], acc[1], acc[2], acc[3]);
    op[1] = make_float4(acc[4], acc[5], acc[6], acc[7]);
  }
}

// ---------------- beta gate + residual (wave per node) ----------------
__global__ void k_beta(const float* __restrict__ ob, const float* __restrict__ xr,
                       const float* __restrict__ Wb, const float* __restrict__ g1p,
                       float* __restrict__ h){
  int n = blockIdx.x * 4 + (threadIdx.x >> 6);
  int lane = threadIdx.x & 63;
  if (n >= NN) return;
  int d = lane * 2;
  const float* op = ob + (size_t)n * 128 + d;
  const float* xp = xr + (size_t)n * 128 + d;
  float o0 = op[0], o1 = op[1], x0 = xp[0], x1 = xp[1];
  float w00 = Wb[d],       w01 = Wb[d + 1];
  float w10 = Wb[128 + d], w11 = Wb[128 + d + 1];
  float w20 = Wb[256 + d], w21 = Wb[256 + d + 1];
  float p = o0 * (w00 + w20) + x0 * (w10 - w20)
          + o1 * (w01 + w21) + x1 * (w11 - w21);
  for (int msk = 1; msk < 64; msk <<= 1) p += __shfl_xor(p, msk);
  float beta = 1.f / (1.f + __expf(-p));
  float g = *g1p;
  float* hp = h + (size_t)n * 128 + d;
  hp[0] += g * (beta * x0 + (1.f - beta) * o0);
  hp[1] += g * (beta * x1 + (1.f - beta) * o1);
}

extern "C" void kernel_launch(void* const* d_in, const int* in_sizes, int n_in,
                              void* d_out, int out_size, void* d_ws, size_t ws_size,
                              hipStream_t stream){
  const float* x    = (const float*)d_in[0];
  const int*   ei   = (const int*)d_in[1];
  const float* Win  = (const float*)d_in[2];
  const float* bin  = (const float*)d_in[3];
  const float* ln1s = (const float*)d_in[4];
  const float* ln1b = (const float*)d_in[5];
  const float* Wq   = (const float*)d_in[6];
  const float* bq   = (const float*)d_in[7];
  const float* Wk   = (const float*)d_in[8];
  const float* bk   = (const float*)d_in[9];
  const float* Wv   = (const float*)d_in[10];
  const float* bv   = (const float*)d_in[11];
  const float* Wsk  = (const float*)d_in[12];
  const float* bsk  = (const float*)d_in[13];
  const float* Wbt  = (const float*)d_in[14];
  const float* ln2s = (const float*)d_in[15];
  const float* ln2b = (const float*)d_in[16];
  const float* W1   = (const float*)d_in[17];
  const float* b1   = (const float*)d_in[18];
  const float* W2   = (const float*)d_in[19];
  const float* b2   = (const float*)d_in[20];
  const float* g1   = (const float*)d_in[21];
  const float* g2   = (const float*)d_in[22];
  const float* lnos = (const float*)d_in[23];
  const float* lnob = (const float*)d_in[24];

  // --- workspace layout in BYTES (total ~88.6 MB) ---
  char* wsb = (char*)d_ws;
  size_t off = 0;
  float*    h   = (float*)(wsb + off);  off += (size_t)NN * 128 * 4;
  float*    hn  = (float*)(wsb + off);  off += (size_t)NN * 128 * 4;
  ushort_t* qb  = (ushort_t*)(wsb + off); off += (size_t)NN * 512 * 2;
  ushort_t* kb  = (ushort_t*)(wsb + off); off += (size_t)NN * 512 * 2;
  float*    xr  = (float*)(wsb + off);  off += (size_t)NN * 128 * 4;
  float*    ob  = (float*)(wsb + off);  off += (size_t)NN * 128 * 4;
  float*    al  = (float*)(wsb + off);  off += (size_t)NE * 4 * 4;
  int*      deg   = (int*)(wsb + off);  off += (size_t)NN * 4;
  int*      rowst = (int*)(wsb + off);  off += (size_t)(NN + 4) * 4;
  int*      cur   = (int*)(wsb + off);  off += (size_t)NN * 4;
  int*      csr   = (int*)(wsb + off);  off += (size_t)NE * 4;
  ushort_t* vb = qb;   // alias: q dead after k_alpha, v produced after
  ushort_t* tb = kb;   // alias: k dead after k_alpha, FFN hidden after k_node

  // CSR build (edge_index is layer-invariant)
  k_zero<<<(NN + 255) / 256, 256, 0, stream>>>(deg, NN);
  k_hist<<<(NE + 255) / 256, 256, 0, stream>>>(ei, deg);
  k_scan<<<1, 1024, 0, stream>>>(deg, rowst, cur);
  k_scatter<<<(NE + 255) / 256, 256, 0, stream>>>(ei, cur, csr);

  k_inproj<<<(NN + 3) / 4, 128, 0, stream>>>(x, Win, bin, h);

  dim3 g512(313, 8), g128(313, 2);
  for (int l = 0; l < 2; l++){
    k_ln<<<(NN + 3) / 4, 256, 0, stream>>>(h, ln1s + l * 128, ln1b + l * 128, hn, NN);
    k_gemm<0,0,1><<<g512, 256, 0, stream>>>(hn, 128, NN, Wq + (size_t)l * 128 * 512, 512, bq + l * 512, qb, 512, 128, nullptr);
    k_gemm<0,0,1><<<g512, 256, 0, stream>>>(hn, 128, NN, Wk + (size_t)l * 128 * 512, 512, bk + l * 512, kb, 512, 128, nullptr);
    k_alpha<<<(NE + 3) / 4, 256, 0, stream>>>(qb, kb, ei, al);
    k_gemm<0,0,1><<<g512, 256, 0, stream>>>(hn, 128, NN, Wv + (size_t)l * 128 * 512, 512, bv + l * 512, vb, 512, 128, nullptr);
    k_gemm<0,0,0><<<g128, 256, 0, stream>>>(hn, 128, NN, Wsk + (size_t)l * 128 * 128, 128, bsk + l * 128, xr, 128, 128, nullptr);
    k_node<<<(NN + 3) / 4, 256, 0, stream>>>(al, vb, ei, rowst, csr, ob);
    k_beta<<<(NN + 3) / 4, 256, 0, stream>>>(ob, xr, Wbt + l * 384, g1 + l, h);
    k_ln<<<(NN + 3) / 4, 256, 0, stream>>>(h, ln2s + l * 128, ln2b + l * 128, hn, NN);
    k_gemm<1,0,1><<<g512, 256, 0, stream>>>(hn, 128, NN, W1 + (size_t)l * 128 * 512, 512, b1 + l * 512, tb, 512, 128, nullptr);
    k_gemm<2,1,0><<<g128, 256, 0, stream>>>(tb, 512, NN, W2 + (size_t)l * 512 * 128, 128, b2 + l * 128, h, 128, 512, g2 + l);
  }
  k_ln<<<(NN + 3) / 4, 256, 0, stream>>>(h, lnos, lnob, (float*)d_out, NN);
}

// Round 5
// 704.070 us; speedup vs baseline: 1.4322x; 1.4322x over previous
//
#include <hip/hip_runtime.h>
#include <hip/hip_bf16.h>
#include <math.h>

#define NN 20000
#define NE 320000

typedef unsigned short ushort_t;
typedef unsigned short ushortx8 __attribute__((ext_vector_type(8)));
typedef short s16x8 __attribute__((ext_vector_type(8)));
typedef float f32x4 __attribute__((ext_vector_type(4)));

__device__ __forceinline__ float us2f(unsigned short u){
  return __uint_as_float(((unsigned)u) << 16);
}
__device__ __forceinline__ unsigned short f2us(float f){
  unsigned u = __float_as_uint(f);
  unsigned r = (u + 0x7fffu + ((u >> 16) & 1u)) >> 16;   // RNE
  return (unsigned short)r;
}

// ---------------- CSR build ----------------
__global__ void k_zero(int* p, int n){
  int i = blockIdx.x * 256 + threadIdx.x;
  if (i < n) p[i] = 0;
}

__global__ void k_hist(const int* __restrict__ ei, int* __restrict__ deg){
  int e = blockIdx.x * 256 + threadIdx.x;
  if (e < NE) atomicAdd(&deg[ei[NE + e]], 1);
}

__global__ __launch_bounds__(1024) void k_scan(const int* __restrict__ deg,
                                               int* __restrict__ rowst,
                                               int* __restrict__ cur){
  __shared__ int s[1024];
  __shared__ int carry_s;
  int tid = threadIdx.x;
  if (tid == 0) carry_s = 0;
  __syncthreads();
  for (int base = 0; base < NN; base += 1024){
    int v = (base + tid < NN) ? deg[base + tid] : 0;
    s[tid] = v; __syncthreads();
    for (int off = 1; off < 1024; off <<= 1){
      int t = (tid >= off) ? s[tid - off] : 0;
      __syncthreads();
      s[tid] += t;
      __syncthreads();
    }
    int carry = carry_s;
    int excl = carry + s[tid] - v;
    if (base + tid < NN){ rowst[base + tid] = excl; cur[base + tid] = excl; }
    __syncthreads();
    if (tid == 0) carry_s = carry + s[1023];
    __syncthreads();
  }
  if (tid == 0) rowst[NN] = carry_s;
}

__global__ void k_scatter(const int* __restrict__ ei, int* __restrict__ cur,
                          int* __restrict__ csr){
  int e = blockIdx.x * 256 + threadIdx.x;
  if (e < NE){
    int d = ei[NE + e];
    int p = atomicAdd(&cur[d], 1);
    csr[p] = e;
  }
}

// ------- weight convert+transpose: all 12 matrices fp32 [K][N] -> bf16 [N][K] -------
// regions (layer-major inside each): Wq(2x128x512) Wk Wv Wsk(2x128x128) W1(2x128x512) W2(2x512x128)
__global__ void k_wt(const float* __restrict__ Wq, const float* __restrict__ Wk,
                     const float* __restrict__ Wv, const float* __restrict__ Wsk,
                     const float* __restrict__ W1, const float* __restrict__ W2,
                     ushort_t* __restrict__ out){
  int f = blockIdx.x * 256 + threadIdx.x;
  if (f >= 688128) return;
  const float* W; ushort_t* dst; int idx, Kd, Nd;
  if (f < 393216){
    int r = f >> 17; idx = f & 131071;
    W = (r == 0) ? Wq : ((r == 1) ? Wk : Wv);
    dst = out + r * 131072; Kd = 128; Nd = 512;
  } else if (f < 425984){
    idx = f - 393216; W = Wsk; dst = out + 393216; Kd = 128; Nd = 128;
  } else if (f < 557056){
    idx = f - 425984; W = W1; dst = out + 425984; Kd = 128; Nd = 512;
  } else {
    idx = f - 557056; W = W2; dst = out + 557056; Kd = 512; Nd = 128;
  }
  int per = Kd * Nd;
  int l = idx / per, r2 = idx % per;
  int n = r2 / Kd, kk = r2 % Kd;
  dst[idx] = f2us(W[(size_t)l * per + (size_t)kk * Nd + n]);
}

// ---------------- input projection: h = x@Win + b_in ----------------
__global__ __launch_bounds__(128) void k_inproj(const float* __restrict__ x,
                                                const float* __restrict__ Win,
                                                const float* __restrict__ bin,
                                                float* __restrict__ h){
  __shared__ float sW[32 * 128];
  __shared__ float sx[4][32];
  int tid = threadIdx.x;
  for (int i = 0; i < 32; i++) sW[i * 128 + tid] = Win[i * 128 + tid];
  int r0 = blockIdx.x * 4;
  {
    int r = tid >> 5, kk = tid & 31;
    int gr = r0 + r;
    sx[r][kk] = (gr < NN) ? x[gr * 32 + kk] : 0.f;
  }
  __syncthreads();
  float bias = bin[tid];
  for (int r = 0; r < 4; r++){
    int gr = r0 + r;
    if (gr >= NN) break;
    float acc = bias;
    #pragma unroll
    for (int k2 = 0; k2 < 32; k2++) acc += sx[r][k2] * sW[k2 * 128 + tid];
    h[(size_t)gr * 128 + tid] = acc;
  }
}

// ---------------- LayerNorm (wave per row); OUTBF16: write bf16 else fp32 ----------------
template<int OUTBF16>
__global__ void k_ln(const float* __restrict__ in, const float* __restrict__ sc,
                     const float* __restrict__ bi, void* __restrict__ outp, int rows){
  int row = blockIdx.x * 4 + (threadIdx.x >> 6);
  int lane = threadIdx.x & 63;
  if (row >= rows) return;
  const float* p = in + (size_t)row * 128 + lane * 2;
  float x0 = p[0], x1 = p[1];
  float sum = x0 + x1;
  for (int m = 1; m < 64; m <<= 1) sum += __shfl_xor(sum, m);
  float mean = sum * (1.f / 128.f);
  float d0 = x0 - mean, d1 = x1 - mean;
  float vs = d0 * d0 + d1 * d1;
  for (int m = 1; m < 64; m <<= 1) vs += __shfl_xor(vs, m);
  float rstd = rsqrtf(vs * (1.f / 128.f) + 1e-5f);
  int d = lane * 2;
  float o0 = d0 * rstd * sc[d] + bi[d];
  float o1 = d1 * rstd * sc[d + 1] + bi[d + 1];
  if (OUTBF16){
    ushort_t* o = (ushort_t*)outp + (size_t)row * 128 + d;
    o[0] = f2us(o0); o[1] = f2us(o1);
  } else {
    float* o = (float*)outp + (size_t)row * 128 + d;
    o[0] = o0; o[1] = o1;
  }
}

// ------- MFMA GEMM: C[M,N] = A[M,K](bf16) @ Bt[N,K](bf16)^T + bias -------
// MODE 0: plain   MODE 1: gelu(exact)   MODE 2: C(f32) += g*(acc+bias)
// CBF16 (MODE 0/1): store bf16, else fp32. 128x128 tile, BK=64, 256 threads.
template<int MODE, int CBF16>
__global__ __launch_bounds__(256) void k_mm(const ushort_t* __restrict__ A, int M, int K,
                                            const ushort_t* __restrict__ Bt,
                                            const float* __restrict__ bias,
                                            void* __restrict__ Cp, int ldc,
                                            const float* __restrict__ gptr){
  __shared__ ushort_t As[128 * 72];   // [m][k], stride 72 (16B-aligned, conflict-benign)
  __shared__ ushort_t Bs[128 * 72];   // [n][k]
  int tid = threadIdx.x;
  int m0 = blockIdx.x * 128, n0 = blockIdx.y * 128;
  int lane = tid & 63, w = tid >> 6;
  int wm = (w >> 1) * 64, wn = (w & 1) * 64;
  int fr = lane & 15, fq = lane >> 4;
  f32x4 acc[4][4];
  #pragma unroll
  for (int i = 0; i < 4; i++)
    #pragma unroll
    for (int j = 0; j < 4; j++) acc[i][j] = (f32x4){0.f, 0.f, 0.f, 0.f};

  for (int k0 = 0; k0 < K; k0 += 64){
    __syncthreads();
    #pragma unroll
    for (int it = 0; it < 4; it++){
      int idx = it * 256 + tid;           // 0..1023
      int row = idx >> 3, ks = (idx & 7) * 8;
      int gr = m0 + row; if (gr >= M) gr = M - 1;
      *(ushortx8*)&As[row * 72 + ks] = *(const ushortx8*)(A + (size_t)gr * K + k0 + ks);
      *(ushortx8*)&Bs[row * 72 + ks] = *(const ushortx8*)(Bt + (size_t)(n0 + row) * K + k0 + ks);
    }
    __syncthreads();
    #pragma unroll
    for (int ks = 0; ks < 64; ks += 32){
      s16x8 a[4], b[4];
      #pragma unroll
      for (int i = 0; i < 4; i++)
        a[i] = *(const s16x8*)&As[(wm + i * 16 + fr) * 72 + ks + fq * 8];
      #pragma unroll
      for (int j = 0; j < 4; j++)
        b[j] = *(const s16x8*)&Bs[(wn + j * 16 + fr) * 72 + ks + fq * 8];
      #pragma unroll
      for (int i = 0; i < 4; i++)
        #pragma unroll
        for (int j = 0; j < 4; j++)
          acc[i][j] = __builtin_amdgcn_mfma_f32_16x16x32_bf16(a[i], b[j], acc[i][j], 0, 0, 0);
    }
  }
  float g = (MODE == 2) ? *gptr : 0.f;
  // C/D layout: col = lane&15, row = 4*(lane>>4) + reg  [m89/m91 verified]
  #pragma unroll
  for (int i = 0; i < 4; i++){
    int grb = m0 + wm + i * 16 + fq * 4;
    #pragma unroll
    for (int r = 0; r < 4; r++){
      int gr = grb + r;
      if (gr >= M) continue;
      #pragma unroll
      for (int j = 0; j < 4; j++){
        int gc = n0 + wn + j * 16 + fr;
        float c = acc[i][j][r] + bias[gc];
        if (MODE == 1) c = 0.5f * c * (1.f + erff(c * 0.70710678118654752f));
        if (MODE == 2){
          float* C = (float*)Cp;
          C[(size_t)gr * ldc + gc] += g * c;
        } else if (CBF16){
          ((ushort_t*)Cp)[(size_t)gr * ldc + gc] = f2us(c);
        } else {
          ((float*)Cp)[(size_t)gr * ldc + gc] = c;
        }
      }
    }
  }
}

// ---------------- per-edge attention logits, CSR-ordered (wave per node) ----------------
__global__ void k_alpha(const ushort_t* __restrict__ q, const ushort_t* __restrict__ k,
                        const int* __restrict__ ei, const int* __restrict__ rowst,
                        const int* __restrict__ csr, float* __restrict__ al){
  int n = blockIdx.x * 4 + (threadIdx.x >> 6);
  int lane = threadIdx.x & 63;
  if (n >= NN) return;
  int s0 = rowst[n], s1 = rowst[n + 1];
  if (s0 == s1) return;
  ushortx8 qv = *((const ushortx8*)(q + (size_t)n * 512) + lane);
  float qf[8];
  #pragma unroll
  for (int t = 0; t < 8; t++) qf[t] = us2f(qv[t]);
  const float scale = 0.08838834764831845f;
  int head = lane >> 4;
  int j = s0;
  for (; j + 2 <= s1; j += 2){
    int e0 = csr[j], e1 = csr[j + 1];
    ushortx8 k0 = *((const ushortx8*)(k + (size_t)ei[e0] * 512) + lane);
    ushortx8 k1 = *((const ushortx8*)(k + (size_t)ei[e1] * 512) + lane);
    float p0 = 0.f, p1 = 0.f;
    #pragma unroll
    for (int t = 0; t < 8; t++){ p0 += qf[t] * us2f(k0[t]); p1 += qf[t] * us2f(k1[t]); }
    p0 += __shfl_xor(p0, 1); p1 += __shfl_xor(p1, 1);
    p0 += __shfl_xor(p0, 2); p1 += __shfl_xor(p1, 2);
    p0 += __shfl_xor(p0, 4); p1 += __shfl_xor(p1, 4);
    p0 += __shfl_xor(p0, 8); p1 += __shfl_xor(p1, 8);
    if ((lane & 15) == 0){
      al[(size_t)e0 * 4 + head] = p0 * scale;
      al[(size_t)e1 * 4 + head] = p1 * scale;
    }
  }
  if (j < s1){
    int e0 = csr[j];
    ushortx8 k0 = *((const ushortx8*)(k + (size_t)ei[e0] * 512) + lane);
    float p0 = 0.f;
    #pragma unroll
    for (int t = 0; t < 8; t++) p0 += qf[t] * us2f(k0[t]);
    p0 += __shfl_xor(p0, 1); p0 += __shfl_xor(p0, 2);
    p0 += __shfl_xor(p0, 4); p0 += __shfl_xor(p0, 8);
    if ((lane & 15) == 0) al[(size_t)e0 * 4 + head] = p0 * scale;
  }
}

// ---------------- per-node softmax + aggregation (wave per node, v in bf16) ----------------
__global__ void k_node(const float* __restrict__ al, const ushort_t* __restrict__ v,
                       const int* __restrict__ ei, const int* __restrict__ rowst,
                       const int* __restrict__ csr, float* __restrict__ ob){
  int n = blockIdx.x * 4 + (threadIdx.x >> 6);
  int lane = threadIdx.x & 63;
  if (n >= NN) return;
  int s0 = rowst[n], s1 = rowst[n + 1];
  int deg = s1 - s0;
  if (deg == 0){
    if (lane < 16){
      float4 z = make_float4(0.f, 0.f, 0.f, 0.f);
      float4* op = (float4*)(ob + (size_t)n * 128 + lane * 8);
      op[0] = z; op[1] = z;
    }
    return;
  }
  int head = lane >> 4, sub = lane & 15;
  float m = -1e30f;
  for (int j = sub; j < deg; j += 16) m = fmaxf(m, al[(size_t)csr[s0 + j] * 4 + head]);
  m = fmaxf(m, __shfl_xor(m, 1)); m = fmaxf(m, __shfl_xor(m, 2));
  m = fmaxf(m, __shfl_xor(m, 4)); m = fmaxf(m, __shfl_xor(m, 8));
  float den = 0.f;
  for (int j = sub; j < deg; j += 16) den += __expf(al[(size_t)csr[s0 + j] * 4 + head] - m);
  den += __shfl_xor(den, 1); den += __shfl_xor(den, 2);
  den += __shfl_xor(den, 4); den += __shfl_xor(den, 8);
  float acc[8] = {0.f, 0.f, 0.f, 0.f, 0.f, 0.f, 0.f, 0.f};
  for (int j = 0; j < deg; j++){
    int e = csr[s0 + j];
    float w = __expf(al[(size_t)e * 4 + head] - m);
    ushortx8 vv = *((const ushortx8*)(v + (size_t)ei[e] * 512) + lane);
    #pragma unroll
    for (int t = 0; t < 8; t++) acc[t] += w * us2f(vv[t]);
  }
  float inv = 0.25f / den;   // mean over 4 heads folded in
  #pragma unroll
  for (int t = 0; t < 8; t++){
    float r = acc[t] * inv;
    r += __shfl_xor(r, 16); r += __shfl_xor(r, 32);
    acc[t] = r;
  }
  if (lane < 16){
    float4* op = (float4*)(ob + (size_t)n * 128 + lane * 8);
    op[0] = make_float4(acc[0], acc[1], acc[2], acc[3]);
    op[1] = make_float4(acc[4], acc[5], acc[6], acc[7]);
  }
}

// ---------------- beta gate + residual (wave per node) ----------------
__global__ void k_beta(const float* __restrict__ ob, const float* __restrict__ xr,
                       const float* __restrict__ Wb, const float* __restrict__ g1p,
                       float* __restrict__ h){
  int n = blockIdx.x * 4 + (threadIdx.x >> 6);
  int lane = threadIdx.x & 63;
  if (n >= NN) return;
  int d = lane * 2;
  const float* op = ob + (size_t)n * 128 + d;
  const float* xp = xr + (size_t)n * 128 + d;
  float o0 = op[0], o1 = op[1], x0 = xp[0], x1 = xp[1];
  float w00 = Wb[d],       w01 = Wb[d + 1];
  float w10 = Wb[128 + d], w11 = Wb[128 + d + 1];
  float w20 = Wb[256 + d], w21 = Wb[256 + d + 1];
  float p = o0 * (w00 + w20) + x0 * (w10 - w20)
          + o1 * (w01 + w21) + x1 * (w11 - w21);
  for (int msk = 1; msk < 64; msk <<= 1) p += __shfl_xor(p, msk);
  float beta = 1.f / (1.f + __expf(-p));
  float g = *g1p;
  float* hp = h + (size_t)n * 128 + d;
  hp[0] += g * (beta * x0 + (1.f - beta) * o0);
  hp[1] += g * (beta * x1 + (1.f - beta) * o1);
}

extern "C" void kernel_launch(void* const* d_in, const int* in_sizes, int n_in,
                              void* d_out, int out_size, void* d_ws, size_t ws_size,
                              hipStream_t stream){
  const float* x    = (const float*)d_in[0];
  const int*   ei   = (const int*)d_in[1];
  const float* Win  = (const float*)d_in[2];
  const float* bin  = (const float*)d_in[3];
  const float* ln1s = (const float*)d_in[4];
  const float* ln1b = (const float*)d_in[5];
  const float* Wq   = (const float*)d_in[6];
  const float* bq   = (const float*)d_in[7];
  const float* Wk   = (const float*)d_in[8];
  const float* bk   = (const float*)d_in[9];
  const float* Wv   = (const float*)d_in[10];
  const float* bv   = (const float*)d_in[11];
  const float* Wsk  = (const float*)d_in[12];
  const float* bsk  = (const float*)d_in[13];
  const float* Wbt  = (const float*)d_in[14];
  const float* ln2s = (const float*)d_in[15];
  const float* ln2b = (const float*)d_in[16];
  const float* W1   = (const float*)d_in[17];
  const float* b1   = (const float*)d_in[18];
  const float* W2   = (const float*)d_in[19];
  const float* b2   = (const float*)d_in[20];
  const float* g1   = (const float*)d_in[21];
  const float* g2   = (const float*)d_in[22];
  const float* lnos = (const float*)d_in[23];
  const float* lnob = (const float*)d_in[24];

  // --- workspace layout in BYTES (~85 MB) ---
  char* wsb = (char*)d_ws;
  size_t off = 0;
  float*    h   = (float*)(wsb + off);    off += (size_t)NN * 128 * 4;
  ushort_t* hn  = (ushort_t*)(wsb + off); off += (size_t)NN * 128 * 2;
  ushort_t* qb  = (ushort_t*)(wsb + off); off += (size_t)NN * 512 * 2;
  ushort_t* kb  = (ushort_t*)(wsb + off); off += (size_t)NN * 512 * 2;
  float*    xr  = (float*)(wsb + off);    off += (size_t)NN * 128 * 4;
  float*    ob  = (float*)(wsb + off);    off += (size_t)NN * 128 * 4;
  float*    al  = (float*)(wsb + off);    off += (size_t)NE * 4 * 4;
  ushort_t* wt  = (ushort_t*)(wsb + off); off += (size_t)688128 * 2;
  int*      deg   = (int*)(wsb + off);    off += (size_t)NN * 4;
  int*      rowst = (int*)(wsb + off);    off += (size_t)(NN + 4) * 4;
  int*      cur   = (int*)(wsb + off);    off += (size_t)NN * 4;
  int*      csr   = (int*)(wsb + off);    off += (size_t)NE * 4;
  ushort_t* vb = qb;   // alias: q dead after k_alpha, v produced after
  ushort_t* tb = kb;   // alias: k dead after k_alpha, FFN hidden after k_node
  // bf16-transposed weight regions [l][n][k]
  ushort_t* Wqt = wt;            // 2x(512x128)
  ushort_t* Wkt = wt + 131072;
  ushort_t* Wvt = wt + 262144;
  ushort_t* Wst = wt + 393216;   // 2x(128x128)
  ushort_t* W1t = wt + 425984;   // 2x(512x128)
  ushort_t* W2t = wt + 557056;   // 2x(128x512)

  // CSR build (edge_index is layer-invariant)
  k_zero<<<(NN + 255) / 256, 256, 0, stream>>>(deg, NN);
  k_hist<<<(NE + 255) / 256, 256, 0, stream>>>(ei, deg);
  k_scan<<<1, 1024, 0, stream>>>(deg, rowst, cur);
  k_scatter<<<(NE + 255) / 256, 256, 0, stream>>>(ei, cur, csr);

  k_wt<<<2688, 256, 0, stream>>>(Wq, Wk, Wv, Wsk, W1, W2, wt);
  k_inproj<<<(NN + 3) / 4, 128, 0, stream>>>(x, Win, bin, h);

  dim3 gB(157, 4), gS(157, 1);
  for (int l = 0; l < 2; l++){
    k_ln<1><<<(NN + 3) / 4, 256, 0, stream>>>(h, ln1s + l * 128, ln1b + l * 128, hn, NN);
    k_mm<0,1><<<gB, 256, 0, stream>>>(hn, NN, 128, Wqt + (size_t)l * 65536, bq + l * 512, qb, 512, nullptr);
    k_mm<0,1><<<gB, 256, 0, stream>>>(hn, NN, 128, Wkt + (size_t)l * 65536, bk + l * 512, kb, 512, nullptr);
    k_alpha<<<(NN + 3) / 4, 256, 0, stream>>>(qb, kb, ei, rowst, csr, al);
    k_mm<0,1><<<gB, 256, 0, stream>>>(hn, NN, 128, Wvt + (size_t)l * 65536, bv + l * 512, vb, 512, nullptr);
    k_mm<0,0><<<gS, 256, 0, stream>>>(hn, NN, 128, Wst + (size_t)l * 16384, bsk + l * 128, xr, 128, nullptr);
    k_node<<<(NN + 3) / 4, 256, 0, stream>>>(al, vb, ei, rowst, csr, ob);
    k_beta<<<(NN + 3) / 4, 256, 0, stream>>>(ob, xr, Wbt + l * 384, g1 + l, h);
    k_ln<1><<<(NN + 3) / 4, 256, 0, stream>>>(h, ln2s + l * 128, ln2b + l * 128, hn, NN);
    k_mm<1,1><<<gB, 256, 0, stream>>>(hn, NN, 128, W1t + (size_t)l * 65536, b1 + l * 512, tb, 512, nullptr);
    k_mm<2,0><<<gS, 256, 0, stream>>>(tb, NN, 512, W2t + (size_t)l * 65536, b2 + l * 128, h, 128, g2 + l);
  }
  k_ln<0><<<(NN + 3) / 4, 256, 0, stream>>>(h, lnos, lnob, (float*)d_out, NN);
}

// Round 6
// 622.571 us; speedup vs baseline: 1.6197x; 1.1309x over previous
//
#include <hip/hip_runtime.h>
#include <hip/hip_bf16.h>
#include <math.h>

#define NN 20000
#define NE 320000

typedef unsigned short ushort_t;
typedef unsigned short ushortx8 __attribute__((ext_vector_type(8)));
typedef short s16x8 __attribute__((ext_vector_type(8)));
typedef float f32x4 __attribute__((ext_vector_type(4)));

__device__ __forceinline__ float us2f(unsigned short u){
  return __uint_as_float(((unsigned)u) << 16);
}
__device__ __forceinline__ unsigned short f2us(float f){
  unsigned u = __float_as_uint(f);
  unsigned r = (u + 0x7fffu + ((u >> 16) & 1u)) >> 16;   // RNE
  return (unsigned short)r;
}

// ---------------- CSR build ----------------
__global__ void k_zero(int* p, int n){
  int i = blockIdx.x * 256 + threadIdx.x;
  if (i < n) p[i] = 0;
}

__global__ void k_hist(const int* __restrict__ ei, int* __restrict__ deg){
  int e = blockIdx.x * 256 + threadIdx.x;
  if (e < NE) atomicAdd(&deg[ei[NE + e]], 1);
}

__global__ __launch_bounds__(1024) void k_scan(const int* __restrict__ deg,
                                               int* __restrict__ rowst,
                                               int* __restrict__ cur){
  __shared__ int s[1024];
  __shared__ int carry_s;
  int tid = threadIdx.x;
  if (tid == 0) carry_s = 0;
  __syncthreads();
  for (int base = 0; base < NN; base += 1024){
    int v = (base + tid < NN) ? deg[base + tid] : 0;
    s[tid] = v; __syncthreads();
    for (int off = 1; off < 1024; off <<= 1){
      int t = (tid >= off) ? s[tid - off] : 0;
      __syncthreads();
      s[tid] += t;
      __syncthreads();
    }
    int carry = carry_s;
    int excl = carry + s[tid] - v;
    if (base + tid < NN){ rowst[base + tid] = excl; cur[base + tid] = excl; }
    __syncthreads();
    if (tid == 0) carry_s = carry + s[1023];
    __syncthreads();
  }
  if (tid == 0) rowst[NN] = carry_s;
}

__global__ void k_scatter(const int* __restrict__ ei, int* __restrict__ cur,
                          int* __restrict__ csr){
  int e = blockIdx.x * 256 + threadIdx.x;
  if (e < NE){
    int d = ei[NE + e];
    int p = atomicAdd(&cur[d], 1);
    csr[p] = e;
  }
}

// ------- weight convert+transpose into bf16 [N][K] regions -------
// layout: Wcat 2x(1664x128) | W1t 2x(512x128) | W2t 2x(128x512)
__global__ void k_wt(const float* __restrict__ Wq, const float* __restrict__ Wk,
                     const float* __restrict__ Wv, const float* __restrict__ Wsk,
                     const float* __restrict__ W1, const float* __restrict__ W2,
                     ushort_t* __restrict__ out){
  int f = blockIdx.x * 256 + threadIdx.x;
  if (f >= 688128) return;
  float val;
  if (f < 425984){
    int l = f / 212992, idx = f % 212992;
    int n = idx / 128, kk = idx % 128;
    if (n < 512)       val = Wq[(size_t)l * 65536 + kk * 512 + n];
    else if (n < 1024) val = Wk[(size_t)l * 65536 + kk * 512 + (n - 512)];
    else if (n < 1536) val = Wv[(size_t)l * 65536 + kk * 512 + (n - 1024)];
    else               val = Wsk[(size_t)l * 16384 + kk * 128 + (n - 1536)];
  } else if (f < 557056){
    int idx = f - 425984;
    int l = idx / 65536, r = idx % 65536;
    int n = r / 128, kk = r % 128;
    val = W1[(size_t)l * 65536 + kk * 512 + n];
  } else {
    int idx = f - 557056;
    int l = idx / 65536, r = idx % 65536;
    int n = r / 512, kk = r % 512;
    val = W2[(size_t)l * 65536 + kk * 128 + n];
  }
  out[f] = f2us(val);
}

__global__ void k_bcat(const float* __restrict__ bq, const float* __restrict__ bk,
                       const float* __restrict__ bv, const float* __restrict__ bsk,
                       float* __restrict__ bcat){
  int i = blockIdx.x * 256 + threadIdx.x;
  if (i >= 3328) return;
  int l = i / 1664, c = i % 1664;
  float v;
  if (c < 512)       v = bq[l * 512 + c];
  else if (c < 1024) v = bk[l * 512 + c - 512];
  else if (c < 1536) v = bv[l * 512 + c - 1024];
  else               v = bsk[l * 128 + c - 1536];
  bcat[i] = v;
}

// ---------------- input projection: h = x@Win + b_in ----------------
__global__ __launch_bounds__(128) void k_inproj(const float* __restrict__ x,
                                                const float* __restrict__ Win,
                                                const float* __restrict__ bin,
                                                float* __restrict__ h){
  __shared__ float sW[32 * 128];
  __shared__ float sx[4][32];
  int tid = threadIdx.x;
  for (int i = 0; i < 32; i++) sW[i * 128 + tid] = Win[i * 128 + tid];
  int r0 = blockIdx.x * 4;
  {
    int r = tid >> 5, kk = tid & 31;
    int gr = r0 + r;
    sx[r][kk] = (gr < NN) ? x[gr * 32 + kk] : 0.f;
  }
  __syncthreads();
  float bias = bin[tid];
  for (int r = 0; r < 4; r++){
    int gr = r0 + r;
    if (gr >= NN) break;
    float acc = bias;
    #pragma unroll
    for (int k2 = 0; k2 < 32; k2++) acc += sx[r][k2] * sW[k2 * 128 + tid];
    h[(size_t)gr * 128 + tid] = acc;
  }
}

// ---------------- LayerNorm (wave per row); OUTBF16: write bf16 else fp32 ----------------
template<int OUTBF16>
__global__ void k_ln(const float* __restrict__ in, const float* __restrict__ sc,
                     const float* __restrict__ bi, void* __restrict__ outp, int rows){
  int row = blockIdx.x * 4 + (threadIdx.x >> 6);
  int lane = threadIdx.x & 63;
  if (row >= rows) return;
  const float* p = in + (size_t)row * 128 + lane * 2;
  float x0 = p[0], x1 = p[1];
  float sum = x0 + x1;
  for (int m = 1; m < 64; m <<= 1) sum += __shfl_xor(sum, m);
  float mean = sum * (1.f / 128.f);
  float d0 = x0 - mean, d1 = x1 - mean;
  float vs = d0 * d0 + d1 * d1;
  for (int m = 1; m < 64; m <<= 1) vs += __shfl_xor(vs, m);
  float rstd = rsqrtf(vs * (1.f / 128.f) + 1e-5f);
  int d = lane * 2;
  float o0 = d0 * rstd * sc[d] + bi[d];
  float o1 = d1 * rstd * sc[d + 1] + bi[d + 1];
  if (OUTBF16){
    ushort_t* o = (ushort_t*)outp + (size_t)row * 128 + d;
    o[0] = f2us(o0); o[1] = f2us(o1);
  } else {
    float* o = (float*)outp + (size_t)row * 128 + d;
    o[0] = o0; o[1] = o1;
  }
}

// ------- MFMA GEMM: C[M,N] = A[M,K](bf16) @ Bt[N,K](bf16)^T + bias -------
// MODE 0: plain   MODE 1: gelu(exact)   MODE 2: C(f32) += g*(acc+bias)
// CBF16 (MODE 0/1): store bf16, else fp32. 128x128 tile, BK=64, 256 threads.
template<int MODE, int CBF16>
__global__ __launch_bounds__(256) void k_mm(const ushort_t* __restrict__ A, int M, int K,
                                            const ushort_t* __restrict__ Bt,
                                            const float* __restrict__ bias,
                                            void* __restrict__ Cp, int ldc,
                                            const float* __restrict__ gptr){
  __shared__ ushort_t As[128 * 72];   // [m][k], stride 72
  __shared__ ushort_t Bs[128 * 72];   // [n][k]
  int tid = threadIdx.x;
  int m0 = blockIdx.x * 128, n0 = blockIdx.y * 128;
  int lane = tid & 63, w = tid >> 6;
  int wm = (w >> 1) * 64, wn = (w & 1) * 64;
  int fr = lane & 15, fq = lane >> 4;
  f32x4 acc[4][4];
  #pragma unroll
  for (int i = 0; i < 4; i++)
    #pragma unroll
    for (int j = 0; j < 4; j++) acc[i][j] = (f32x4){0.f, 0.f, 0.f, 0.f};

  for (int k0 = 0; k0 < K; k0 += 64){
    __syncthreads();
    #pragma unroll
    for (int it = 0; it < 4; it++){
      int idx = it * 256 + tid;           // 0..1023
      int row = idx >> 3, ks = (idx & 7) * 8;
      int gr = m0 + row; if (gr >= M) gr = M - 1;
      *(ushortx8*)&As[row * 72 + ks] = *(const ushortx8*)(A + (size_t)gr * K + k0 + ks);
      *(ushortx8*)&Bs[row * 72 + ks] = *(const ushortx8*)(Bt + (size_t)(n0 + row) * K + k0 + ks);
    }
    __syncthreads();
    #pragma unroll
    for (int ks = 0; ks < 64; ks += 32){
      s16x8 a[4], b[4];
      #pragma unroll
      for (int i = 0; i < 4; i++)
        a[i] = *(const s16x8*)&As[(wm + i * 16 + fr) * 72 + ks + fq * 8];
      #pragma unroll
      for (int j = 0; j < 4; j++)
        b[j] = *(const s16x8*)&Bs[(wn + j * 16 + fr) * 72 + ks + fq * 8];
      #pragma unroll
      for (int i = 0; i < 4; i++)
        #pragma unroll
        for (int j = 0; j < 4; j++)
          acc[i][j] = __builtin_amdgcn_mfma_f32_16x16x32_bf16(a[i], b[j], acc[i][j], 0, 0, 0);
    }
  }
  float g = (MODE == 2) ? *gptr : 0.f;
  // C/D layout: col = lane&15, row = 4*(lane>>4) + reg
  #pragma unroll
  for (int i = 0; i < 4; i++){
    int grb = m0 + wm + i * 16 + fq * 4;
    #pragma unroll
    for (int r = 0; r < 4; r++){
      int gr = grb + r;
      if (gr >= M) continue;
      #pragma unroll
      for (int j = 0; j < 4; j++){
        int gc = n0 + wn + j * 16 + fr;
        float c = acc[i][j][r] + bias[gc];
        if (MODE == 1) c = 0.5f * c * (1.f + erff(c * 0.70710678118654752f));
        if (MODE == 2){
          ((float*)Cp)[(size_t)gr * ldc + gc] += g * c;
        } else if (CBF16){
          ((ushort_t*)Cp)[(size_t)gr * ldc + gc] = f2us(c);
        } else {
          ((float*)Cp)[(size_t)gr * ldc + gc] = c;
        }
      }
    }
  }
}

// ---- per-edge attention logits, CSR-ordered, unroll-4 (wave per node) ----
// qkv row stride 1664: q at +0, k at +512
__global__ void k_alpha(const ushort_t* __restrict__ qkv, const int* __restrict__ ei,
                        const int* __restrict__ rowst, const int* __restrict__ csr,
                        float* __restrict__ al){
  int n = blockIdx.x * 4 + (threadIdx.x >> 6);
  int lane = threadIdx.x & 63;
  if (n >= NN) return;
  int s0 = rowst[n], s1 = rowst[n + 1];
  if (s0 == s1) return;
  ushortx8 qv = *((const ushortx8*)(qkv + (size_t)n * 1664) + lane);
  float qf[8];
  #pragma unroll
  for (int t = 0; t < 8; t++) qf[t] = us2f(qv[t]);
  const float scale = 0.08838834764831845f;
  int head = lane >> 4;
  int j = s0;
  for (; j + 4 <= s1; j += 4){
    int e[4], sv[4];
    #pragma unroll
    for (int u = 0; u < 4; u++) e[u] = csr[j + u];
    #pragma unroll
    for (int u = 0; u < 4; u++) sv[u] = ei[e[u]];
    ushortx8 kv[4];
    #pragma unroll
    for (int u = 0; u < 4; u++)
      kv[u] = *((const ushortx8*)(qkv + (size_t)sv[u] * 1664 + 512) + lane);
    float p[4] = {0.f, 0.f, 0.f, 0.f};
    #pragma unroll
    for (int u = 0; u < 4; u++)
      #pragma unroll
      for (int t = 0; t < 8; t++) p[u] += qf[t] * us2f(kv[u][t]);
    #pragma unroll
    for (int u = 0; u < 4; u++){
      p[u] += __shfl_xor(p[u], 1); p[u] += __shfl_xor(p[u], 2);
      p[u] += __shfl_xor(p[u], 4); p[u] += __shfl_xor(p[u], 8);
    }
    if ((lane & 15) == 0){
      #pragma unroll
      for (int u = 0; u < 4; u++) al[(size_t)e[u] * 4 + head] = p[u] * scale;
    }
  }
  for (; j < s1; j++){
    int e0 = csr[j];
    ushortx8 kv0 = *((const ushortx8*)(qkv + (size_t)ei[e0] * 1664 + 512) + lane);
    float p0 = 0.f;
    #pragma unroll
    for (int t = 0; t < 8; t++) p0 += qf[t] * us2f(kv0[t]);
    p0 += __shfl_xor(p0, 1); p0 += __shfl_xor(p0, 2);
    p0 += __shfl_xor(p0, 4); p0 += __shfl_xor(p0, 8);
    if ((lane & 15) == 0) al[(size_t)e0 * 4 + head] = p0 * scale;
  }
}

// ---- per-node softmax + aggregation, unroll-4 (wave per node); v at qkv+1024 ----
__global__ void k_node(const float* __restrict__ al, const ushort_t* __restrict__ qkv,
                       const int* __restrict__ ei, const int* __restrict__ rowst,
                       const int* __restrict__ csr, float* __restrict__ ob){
  int n = blockIdx.x * 4 + (threadIdx.x >> 6);
  int lane = threadIdx.x & 63;
  if (n >= NN) return;
  int s0 = rowst[n], s1 = rowst[n + 1];
  int deg = s1 - s0;
  if (deg == 0){
    if (lane < 16){
      float4 z = make_float4(0.f, 0.f, 0.f, 0.f);
      float4* op = (float4*)(ob + (size_t)n * 128 + lane * 8);
      op[0] = z; op[1] = z;
    }
    return;
  }
  int head = lane >> 4, sub = lane & 15;
  float m = -1e30f;
  for (int j = sub; j < deg; j += 16) m = fmaxf(m, al[(size_t)csr[s0 + j] * 4 + head]);
  m = fmaxf(m, __shfl_xor(m, 1)); m = fmaxf(m, __shfl_xor(m, 2));
  m = fmaxf(m, __shfl_xor(m, 4)); m = fmaxf(m, __shfl_xor(m, 8));
  float den = 0.f;
  for (int j = sub; j < deg; j += 16) den += __expf(al[(size_t)csr[s0 + j] * 4 + head] - m);
  den += __shfl_xor(den, 1); den += __shfl_xor(den, 2);
  den += __shfl_xor(den, 4); den += __shfl_xor(den, 8);
  float acc[8] = {0.f, 0.f, 0.f, 0.f, 0.f, 0.f, 0.f, 0.f};
  int j = s0;
  for (; j + 4 <= s1; j += 4){
    int e[4], sv[4];
    #pragma unroll
    for (int u = 0; u < 4; u++) e[u] = csr[j + u];
    #pragma unroll
    for (int u = 0; u < 4; u++) sv[u] = ei[e[u]];
    float w[4];
    #pragma unroll
    for (int u = 0; u < 4; u++) w[u] = al[(size_t)e[u] * 4 + head];
    ushortx8 vv[4];
    #pragma unroll
    for (int u = 0; u < 4; u++)
      vv[u] = *((const ushortx8*)(qkv + (size_t)sv[u] * 1664 + 1024) + lane);
    #pragma unroll
    for (int u = 0; u < 4; u++){
      float ww = __expf(w[u] - m);
      #pragma unroll
      for (int t = 0; t < 8; t++) acc[t] += ww * us2f(vv[u][t]);
    }
  }
  for (; j < s1; j++){
    int e0 = csr[j];
    float ww = __expf(al[(size_t)e0 * 4 + head] - m);
    ushortx8 vv = *((const ushortx8*)(qkv + (size_t)ei[e0] * 1664 + 1024) + lane);
    #pragma unroll
    for (int t = 0; t < 8; t++) acc[t] += ww * us2f(vv[t]);
  }
  float inv = 0.25f / den;   // mean over 4 heads folded in
  #pragma unroll
  for (int t = 0; t < 8; t++){
    float r = acc[t] * inv;
    r += __shfl_xor(r, 16); r += __shfl_xor(r, 32);
    acc[t] = r;
  }
  if (lane < 16){
    float4* op = (float4*)(ob + (size_t)n * 128 + lane * 8);
    op[0] = make_float4(acc[0], acc[1], acc[2], acc[3]);
    op[1] = make_float4(acc[4], acc[5], acc[6], acc[7]);
  }
}

// ---------------- beta gate + residual (wave per node); xr bf16 at qkv+1536 ----------------
__global__ void k_beta(const float* __restrict__ ob, const ushort_t* __restrict__ qkv,
                       const float* __restrict__ Wb, const float* __restrict__ g1p,
                       float* __restrict__ h){
  int n = blockIdx.x * 4 + (threadIdx.x >> 6);
  int lane = threadIdx.x & 63;
  if (n >= NN) return;
  int d = lane * 2;
  const float* op = ob + (size_t)n * 128 + d;
  const ushort_t* xp = qkv + (size_t)n * 1664 + 1536 + d;
  float o0 = op[0], o1 = op[1];
  float x0 = us2f(xp[0]), x1 = us2f(xp[1]);
  float w00 = Wb[d],       w01 = Wb[d + 1];
  float w10 = Wb[128 + d], w11 = Wb[128 + d + 1];
  float w20 = Wb[256 + d], w21 = Wb[256 + d + 1];
  float p = o0 * (w00 + w20) + x0 * (w10 - w20)
          + o1 * (w01 + w21) + x1 * (w11 - w21);
  for (int msk = 1; msk < 64; msk <<= 1) p += __shfl_xor(p, msk);
  float beta = 1.f / (1.f + __expf(-p));
  float g = *g1p;
  float* hp = h + (size_t)n * 128 + d;
  hp[0] += g * (beta * x0 + (1.f - beta) * o0);
  hp[1] += g * (beta * x1 + (1.f - beta) * o1);
}

extern "C" void kernel_launch(void* const* d_in, const int* in_sizes, int n_in,
                              void* d_out, int out_size, void* d_ws, size_t ws_size,
                              hipStream_t stream){
  const float* x    = (const float*)d_in[0];
  const int*   ei   = (const int*)d_in[1];
  const float* Win  = (const float*)d_in[2];
  const float* bin  = (const float*)d_in[3];
  const float* ln1s = (const float*)d_in[4];
  const float* ln1b = (const float*)d_in[5];
  const float* Wq   = (const float*)d_in[6];
  const float* bq   = (const float*)d_in[7];
  const float* Wk   = (const float*)d_in[8];
  const float* bk   = (const float*)d_in[9];
  const float* Wv   = (const float*)d_in[10];
  const float* bv   = (const float*)d_in[11];
  const float* Wsk  = (const float*)d_in[12];
  const float* bsk  = (const float*)d_in[13];
  const float* Wbt  = (const float*)d_in[14];
  const float* ln2s = (const float*)d_in[15];
  const float* ln2b = (const float*)d_in[16];
  const float* W1   = (const float*)d_in[17];
  const float* b1   = (const float*)d_in[18];
  const float* W2   = (const float*)d_in[19];
  const float* b2   = (const float*)d_in[20];
  const float* g1   = (const float*)d_in[21];
  const float* g2   = (const float*)d_in[22];
  const float* lnos = (const float*)d_in[23];
  const float* lnob = (const float*)d_in[24];

  // --- workspace layout in BYTES (~121 MB; ws_size >= 170 MB established) ---
  char* wsb = (char*)d_ws;
  size_t off = 0;
  float*    h    = (float*)(wsb + off);    off += (size_t)NN * 128 * 4;     // 10.24 MB
  ushort_t* hn   = (ushort_t*)(wsb + off); off += (size_t)NN * 128 * 2;     // 5.12 MB
  ushort_t* qkvs = (ushort_t*)(wsb + off); off += (size_t)NN * 1664 * 2;    // 66.56 MB
  ushort_t* tb   = (ushort_t*)(wsb + off); off += (size_t)NN * 512 * 2;     // 20.48 MB
  float*    ob   = (float*)(wsb + off);    off += (size_t)NN * 128 * 4;     // 10.24 MB
  float*    al   = (float*)(wsb + off);    off += (size_t)NE * 4 * 4;       // 5.12 MB
  ushort_t* wt   = (ushort_t*)(wsb + off); off += (size_t)688128 * 2;       // 1.38 MB
  float*    bcat = (float*)(wsb + off);    off += (size_t)3328 * 4;
  int*      deg   = (int*)(wsb + off);     off += (size_t)NN * 4;
  int*      rowst = (int*)(wsb + off);     off += (size_t)(NN + 4) * 4;
  int*      cur   = (int*)(wsb + off);     off += (size_t)NN * 4;
  int*      csr   = (int*)(wsb + off);     off += (size_t)NE * 4;
  ushort_t* Wcat = wt;                 // 2x(1664x128)
  ushort_t* W1t  = wt + 425984;        // 2x(512x128)
  ushort_t* W2t  = wt + 557056;        // 2x(128x512)

  // CSR build (edge_index is layer-invariant)
  k_zero<<<(NN + 255) / 256, 256, 0, stream>>>(deg, NN);
  k_hist<<<(NE + 255) / 256, 256, 0, stream>>>(ei, deg);
  k_scan<<<1, 1024, 0, stream>>>(deg, rowst, cur);
  k_scatter<<<(NE + 255) / 256, 256, 0, stream>>>(ei, cur, csr);

  k_wt<<<2688, 256, 0, stream>>>(Wq, Wk, Wv, Wsk, W1, W2, wt);
  k_bcat<<<13, 256, 0, stream>>>(bq, bk, bv, bsk, bcat);
  k_inproj<<<(NN + 3) / 4, 128, 0, stream>>>(x, Win, bin, h);

  dim3 gQ(157, 13), gF1(157, 4), gF2(157, 1);
  for (int l = 0; l < 2; l++){
    k_ln<1><<<(NN + 3) / 4, 256, 0, stream>>>(h, ln1s + l * 128, ln1b + l * 128, hn, NN);
    k_mm<0,1><<<gQ, 256, 0, stream>>>(hn, NN, 128, Wcat + (size_t)l * 212992, bcat + l * 1664, qkvs, 1664, nullptr);
    k_alpha<<<(NN + 3) / 4, 256, 0, stream>>>(qkvs, ei, rowst, csr, al);
    k_node<<<(NN + 3) / 4, 256, 0, stream>>>(al, qkvs, ei, rowst, csr, ob);
    k_beta<<<(NN + 3) / 4, 256, 0, stream>>>(ob, qkvs, Wbt + l * 384, g1 + l, h);
    k_ln<1><<<(NN + 3) / 4, 256, 0, stream>>>(h, ln2s + l * 128, ln2b + l * 128, hn, NN);
    k_mm<1,1><<<gF1, 256, 0, stream>>>(hn, NN, 128, W1t + (size_t)l * 65536, b1 + l * 512, tb, 512, nullptr);
    k_mm<2,0><<<gF2, 256, 0, stream>>>(tb, NN, 512, W2t + (size_t)l * 65536, b2 + l * 128, h, 128, g2 + l);
  }
  k_ln<0><<<(NN + 3) / 4, 256, 0, stream>>>(h, lnos, lnob, (float*)d_out, NN);
}